// Round 1
// 251.077 us; speedup vs baseline: 1.0104x; 1.0104x over previous
//
#include <hip/hip_runtime.h>
#include <math.h>

constexpr int L = 256;
constexpr float EPS = 1e-6f;

typedef float f32x4 __attribute__((ext_vector_type(4)));

__device__ inline float wave_sum(float v) {
#pragma unroll
    for (int off = 32; off > 0; off >>= 1) v += __shfl_down(v, off, 64);
    return v;
}
__device__ inline int wave_min(int v) {
#pragma unroll
    for (int off = 32; off > 0; off >>= 1) v = min(v, __shfl_down(v, off, 64));
    return v;
}
__device__ inline int wave_max(int v) {
#pragma unroll
    for (int off = 32; off > 0; off >>= 1) v = max(v, __shfl_down(v, off, 64));
    return v;
}

// Fused per-sample kernel: one 512-thread block streams its whole sample in a
// single 8-iteration 4+4 register double-buffer pass (each thread: 32 float4
// per array), then computes box + generated-mask sum + ratio inline.
// 512 threads/block doubles occupancy vs the 256-thread version:
// 2 blocks/CU x 8 waves = 16 waves/CU = 4 waves/SIMD (was 2/SIMD, grid-limited).
__global__ __launch_bounds__(512, 4) void sample_kernel(
    const float* __restrict__ Yp, const float* __restrict__ Yg,
    float* __restrict__ ratios) {
    const int b = blockIdx.x;
    const int t = threadIdx.x;
    const float* yp = Yp + (size_t)b * L * L;

    // Geometry (data-independent): float4 idx j = it*2048 + k*512 + t
    //   row(it,k) = (t>>6) + 8*(it*4+k) ; cols c0..c0+3, c0=(t&63)*4
    const int w = t >> 6;              // wave id 0..7 == row base
    const int c0 = (t & 63) << 2;

    const f32x4* yp4 = (const f32x4*)yp;
    const f32x4* yg4 = (const f32x4*)(Yg + (size_t)b * L * L);

    float sum_p = 0.f, sum_pg = 0.f;
    int anyg_t = 0;
    unsigned cb0 = 0, cb1 = 0, cb2 = 0, cb3 = 0;  // per-column presence
    unsigned rowbits = 0u;                         // bit n -> row w + 8n

    // Prologue: load iteration 0's 4+4 float4.
    f32x4 Pc[4], Gc[4], Pn[4], Gn[4];
#pragma unroll
    for (int k = 0; k < 4; ++k) {
        Pc[k] = __builtin_nontemporal_load(yp4 + (k << 9) + t);
        Gc[k] = __builtin_nontemporal_load(yg4 + (k << 9) + t);
    }

#pragma unroll
    for (int it = 0; it < 8; ++it) {
        if (it < 7) {  // next iteration's loads in flight while consuming
#pragma unroll
            for (int k = 0; k < 4; ++k) {
                const int off = ((it + 1) << 11) + (k << 9) + t;
                Pn[k] = __builtin_nontemporal_load(yp4 + off);
                Gn[k] = __builtin_nontemporal_load(yg4 + off);
            }
        }
#pragma unroll
        for (int k = 0; k < 4; ++k) {
            const f32x4 p = Pc[k], g = Gc[k];
            sum_p  += (p[0] + p[1]) + (p[2] + p[3]);
            sum_pg += p[0] * g[0] + p[1] * g[1] + p[2] * g[2] + p[3] * g[3];
            anyg_t |= (g[0] > 0.f) | (g[1] > 0.f) | (g[2] > 0.f) | (g[3] > 0.f);
            const unsigned bx = p[0] > 0.5f, by = p[1] > 0.5f,
                           bz = p[2] > 0.5f, bw = p[3] > 0.5f;
            rowbits |= (bx | by | bz | bw) << (it * 4 + k);
            cb0 |= bx; cb1 |= by; cb2 |= bz; cb3 |= bw;
        }
#pragma unroll
        for (int k = 0; k < 4; ++k) { Pc[k] = Pn[k]; Gc[k] = Gn[k]; }
    }

    int minr = 0x7FFFFFFF, maxr = -1;
    if (rowbits) {
        minr = w + 8 * __builtin_ctz(rowbits);
        maxr = w + 8 * (31 - __builtin_clz(rowbits));
    }

    // Column candidates from accumulated per-column presence.
    int minc = 0x7FFFFFFF, maxc = -1;
    const unsigned colbits = cb0 | (cb1 << 1) | (cb2 << 2) | (cb3 << 3);
    if (colbits) {
        minc = c0 + __builtin_ctz(colbits);
        maxc = c0 + (31 - __builtin_clz(colbits));
    }

    // Wave reduce, then LDS across the 8 waves.
    const int wave = t >> 6, lane = t & 63;
    const float wsp = wave_sum(sum_p);
    const float wspg = wave_sum(sum_pg);
    const int wanyg = __any(anyg_t);
    const int wminr = wave_min(minr), wmaxr = wave_max(maxr);
    const int wminc = wave_min(minc), wmaxc = wave_max(maxc);

    __shared__ float sh_p[8], sh_pg[8];
    __shared__ int sh_a[8], sh_minr[8], sh_maxr[8], sh_minc[8], sh_maxc[8];
    if (lane == 0) {
        sh_p[wave] = wsp; sh_pg[wave] = wspg; sh_a[wave] = wanyg;
        sh_minr[wave] = wminr; sh_maxr[wave] = wmaxr;
        sh_minc[wave] = wminc; sh_maxc[wave] = wmaxc;
    }
    __syncthreads();

    // Merge block-level stats redundantly on all threads.
    float sp = 0.f, spg = 0.f;
    int anyg = 0, mnr = 0x7FFFFFFF, mxr = -1, mnc = 0x7FFFFFFF, mxc = -1;
#pragma unroll
    for (int i = 0; i < 8; ++i) {
        sp += sh_p[i]; spg += sh_pg[i]; anyg |= sh_a[i];
        mnr = min(mnr, sh_minr[i]); mxr = max(mxr, sh_maxr[i]);
        mnc = min(mnc, sh_minc[i]); mxc = max(mxc, sh_maxc[i]);
    }

    // Faithful to reference (incl. the row/col swap and Python floor division).
    const bool any_r = mxr >= 0, any_c = mxc >= 0;
    const int left  = any_r ? mnr : 0;
    const int right = any_r ? (L - 1 - mxr) : 0;
    const int up    = any_c ? mnc : 0;
    const int down  = any_c ? (L - 1 - mxc) : 0;
    const int x_r = (right - left) >> 1;   // arithmetic shift = floor div
    const int y_r = (down - up) >> 1;
    const float gt0 = (float)(left + x_r); // compared against COLUMN coord
    const float gt1 = (float)(up + y_r);   // compared against ROW coord

    // Generated-mask branch: tiny bounded loop over the mask box (all threads,
    // block-uniform condition). Mask empty if x_r==0 or y_r==0 (inf/nan -> h
    // not > 0.1 in the reference).
    const bool gen = (!anyg) && (x_r != 0) && (y_r != 0);
    float pos = 0.f;
    if (gen) {
        const float inv_xr = 1.f / (float)x_r;
        const float inv_yr = 1.f / (float)y_r;
        // mask needs d0^4+d1^4 < ln(10)*4/9 => |d| <= 1.0059 ; pad a bit
        const float mx = fabsf((float)x_r) * 1.02f + 1.f;
        const float my = fabsf((float)y_r) * 1.02f + 1.f;
        const int cl = max(0, (int)floorf(gt0 - mx));
        const int ch = min(L - 1, (int)ceilf(gt0 + mx));
        const int rl = max(0, (int)floorf(gt1 - my));
        const int rh = min(L - 1, (int)ceilf(gt1 + my));
        const int W = ch - cl + 1, H = rh - rl + 1;
        for (int idx = t; idx < W * H; idx += 512) {
            const int r = rl + idx / W;
            const int c = cl + idx % W;
            float d0 = ((float)c - gt0) * inv_xr;
            float d1 = ((float)r - gt1) * inv_yr;
            d0 *= d0; d0 *= d0;    // d0^4
            d1 *= d1; d1 *= d1;    // d1^4
            const float h = __expf(-2.25f * (d0 + d1));  // exp(-h'/(2/3)^2)
            if (h > 0.1f) pos += yp[r * L + c];
        }
    }
    __syncthreads();  // everyone has read sh_* ; safe to reuse sh_p
    const float wpos = wave_sum(pos);
    if (lane == 0) sh_p[wave] = wpos;
    __syncthreads();
    if (t == 0) {
        float posg = 0.f;
#pragma unroll
        for (int i = 0; i < 8; ++i) posg += sh_p[i];
        const float positive = anyg ? spg : (gen ? posg : 0.f);
        ratios[b] = (sp - positive) / (positive + EPS);
    }
}

__global__ __launch_bounds__(256) void finalize_kernel(
    const float* __restrict__ ratios, float* __restrict__ out, int B) {
    float v = 0.f;
    for (int i = threadIdx.x; i < B; i += 256) v += ratios[i];
    v = wave_sum(v);
    __shared__ float part[4];
    const int wave = threadIdx.x >> 6, lane = threadIdx.x & 63;
    if (lane == 0) part[wave] = v;
    __syncthreads();
    if (threadIdx.x == 0) {
        const float total = part[0] + part[1] + part[2] + part[3];
        out[0] = (total == 0.f) ? 0.f : logf(total) / (float)B;
    }
}

extern "C" void kernel_launch(void* const* d_in, const int* in_sizes, int n_in,
                              void* d_out, int out_size, void* d_ws, size_t ws_size,
                              hipStream_t stream) {
    const float* Yp = (const float*)d_in[0];
    const float* Yg = (const float*)d_in[1];
    const int B = in_sizes[0] / (L * L);
    float* ratios = (float*)d_ws;   // B floats of scratch
    sample_kernel<<<B, 512, 0, stream>>>(Yp, Yg, ratios);
    finalize_kernel<<<1, 256, 0, stream>>>(ratios, (float*)d_out, B);
}